// Round 11
// baseline (548.020 us; speedup 1.0000x reference)
//
#include <hip/hip_runtime.h>

// ===========================================================================
// ViewGCNEncoder r26 = r25 + PANEL-MAJOR SpMM (beats the "8xG compulsory"
// FETCH floor, which was layout-induced, not fundamental):
//   G stored panel-major Gp[panel][row][32] (panel 3.2MB <= 4MB XCD L2).
//   spmmp block = (row-group of 8) x (panel of 32 feats); panel=blockIdx%np
//   -> panel p resident in one XCD's L2 (np=8 at D=256); gathers L2-hit.
//   Half-wave per row (32 lanes x 32 feats), 8-deep edge chunks, LDS-staged
//   frag flush (128B quad segments, full lines). GEMMs write panel-major.
// L1 FETCH: G 205->25.6MB, ecv 6.4->51MB (net 208->~130MB).
// Kept: r25 atomic-free scatter, lookback scan, pass2+GEMM1 fusion.
// 10 launches. Workspace ~89 MB.
// ===========================================================================

typedef unsigned short ushort_t;
typedef __attribute__((ext_vector_type(8))) short bf16x8;   // 8 bf16 = 4 VGPRs
typedef __attribute__((ext_vector_type(4))) float f32x4;
typedef __attribute__((ext_vector_type(2))) unsigned int u32x2;
typedef __attribute__((ext_vector_type(4))) unsigned int u32x4;

__device__ __forceinline__ float bf2f(ushort_t u) {
  return __uint_as_float(((unsigned int)u) << 16);
}
__device__ __forceinline__ ushort_t f2bf(float f) {
  unsigned int u = __float_as_uint(f);
  return (ushort_t)((u + 0x7FFFu + ((u >> 16) & 1u)) >> 16);  // RNE
}
__device__ __forceinline__ float read_f(const void* p, int fm, size_t i) {
  return fm ? bf2f(((const ushort_t*)p)[i]) : ((const float*)p)[i];
}

// fragment-order offset: tile-major 16-row tiles; within tile kc-chunk(32 k)
// then lane-linear (lane = (m&15)+16*((k>>3)&3), 8 elems each).
__device__ __forceinline__ size_t frag_off(int m, int k, int K) {
  return (size_t)(m >> 4) * 16 * K + ((size_t)(k >> 5) << 9) +
         (((k >> 3) & 3) << 7) + ((m & 15) << 3) + (k & 7);
}

// ---------------- prep: sniff (0-2) + W/bias convert (3-34) + zero (35+) ---
__global__ void prep_kernel(const void* __restrict__ x,
                            const void* __restrict__ m1,
                            const void* __restrict__ m2,
                            int* __restrict__ modes,
                            int* __restrict__ zero_region, int zn,
                            const void* __restrict__ W1, const void* __restrict__ W2,
                            const void* __restrict__ W3,
                            const void* __restrict__ b1, const void* __restrict__ b2,
                            const void* __restrict__ b3,
                            ushort_t* __restrict__ whi, ushort_t* __restrict__ wlo,
                            float* __restrict__ biasf,
                            int n1, int n2, int n3, int h1, int h2, int h3,
                            int K1, int K2, int K3) {
  if (blockIdx.x == 0) {
    __shared__ int bfok;
    if (threadIdx.x == 0) bfok = 1;
    __syncthreads();
    for (int i = threadIdx.x; i < 8192; i += blockDim.x) {
      ushort_t h = ((const ushort_t*)x)[i];
      int e = (h >> 7) & 0xFF;
      if (!(h == 0 || (e >= 95 && e <= 133))) atomicAnd(&bfok, 0);
    }
    __syncthreads();
    if (threadIdx.x == 0) modes[0] = bfok;   // 1=bf16, 0=f32
  } else if (blockIdx.x <= 2) {
    const void* p = (blockIdx.x == 1) ? m1 : m2;
    __shared__ int ok[4];  // [i32, f32, bf16, u8]
    if (threadIdx.x < 4) ok[threadIdx.x] = 1;
    __syncthreads();
    for (int i = threadIdx.x; i < 4096; i += blockDim.x) {
      unsigned int w = ((const unsigned int*)p)[i];
      if (!(w == 0u || w == 1u)) atomicAnd(&ok[0], 0);
      if (!(w == 0u || w == 0x3F800000u)) atomicAnd(&ok[1], 0);
      unsigned int h16 = w >> 16, l16 = w & 0xFFFFu;
      if (!((h16 == 0u || h16 == 0x3F80u) && (l16 == 0u || l16 == 0x3F80u)))
        atomicAnd(&ok[2], 0);
      if (((w | (w >> 8) | (w >> 16) | (w >> 24)) & 0xFEu) != 0u) atomicAnd(&ok[3], 0);
    }
    __syncthreads();
    if (threadIdx.x == 0)
      modes[blockIdx.x] = ok[0] ? 1 : (ok[1] ? 2 : (ok[2] ? 3 : 0));
  } else if (blockIdx.x < 35) {
    // W split + bias convert; self-sniff x dtype (weights share x's dtype)
    __shared__ int bfok;
    if (threadIdx.x == 0) bfok = 1;
    __syncthreads();
    for (int i = threadIdx.x; i < 8192; i += blockDim.x) {
      ushort_t h = ((const ushort_t*)x)[i];
      int e = (h >> 7) & 0xFF;
      if (!(h == 0 || (e >= 95 && e <= 133))) atomicAnd(&bfok, 0);
    }
    __syncthreads();
    int fm = bfok;
    int wtot = n1 + n2 + n3;
    int total = wtot + h1 + h2 + h3;
    for (int i = (blockIdx.x - 3) * 256 + threadIdx.x; i < total; i += 32 * 256) {
      if (i < wtot) {
        const void* src; int j, K; size_t base;
        if (i < n1) { src = W1; j = i; K = K1; base = 0; }
        else if (i < n1 + n2) { src = W2; j = i - n1; K = K2; base = n1; }
        else { src = W3; j = i - n1 - n2; K = K3; base = (size_t)n1 + n2; }
        int n = j / K, k = j - n * K;
        float v = read_f(src, fm, j);
        ushort_t h = f2bf(v);
        size_t o = base + frag_off(n, k, K);
        whi[o] = h;
        wlo[o] = f2bf(v - bf2f(h));
      } else {
        int k = i - wtot;
        const void* src; int j;
        if (k < h1) { src = b1; j = k; }
        else if (k < h1 + h2) { src = b2; j = k - h1; }
        else { src = b3; j = k - h1 - h2; }
        biasf[k] = read_f(src, fm, j);
      }
    }
  } else {
    int i = (blockIdx.x - 35) * blockDim.x + threadIdx.x;
    int stride = (gridDim.x - 35) * blockDim.x;
    for (; i < zn; i += stride) zero_region[i] = 0;
  }
}

// ---------------- pass 1: tile-binning, LDS-staged flush (no edge atomics) --
__global__ void hist_bin_kernel(
    const int* __restrict__ rows, const int* __restrict__ cols,
    const void* __restrict__ vals, const int* __restrict__ fm_p,
    int* __restrict__ h8, int* __restrict__ cnt_ovf, int* __restrict__ binfill,
    int2* __restrict__ bins, int cap, int use_bins, int4* __restrict__ ovf,
    int E, int Nrows, const void* __restrict__ x, ushort_t* __restrict__ xbf,
    int K1, int nx) {
  int fm = *fm_p;
  const int BIN_BLOCKS = 1024;
  if (blockIdx.x < BIN_BLOCKS) {
    int xcd = blockIdx.x & 7;
    if (use_bins) {
      __shared__ int hist[8];
      __shared__ int gbase[8];
      __shared__ int pfx[8];
      __shared__ int2 stage[1024];
      int tid = threadIdx.x;
      for (int tb = blockIdx.x; tb * 1024 < E; tb += BIN_BLOCKS) {
        int base = tb * 1024;
        if (tid < 8) hist[tid] = 0;
        __syncthreads();
        int rr[4], cc[4], pp[4], rk[4]; float vv[4];
#pragma unroll
        for (int j = 0; j < 4; ++j) {
          int i = base + j * 256 + tid;
          if (i < E) {
            rr[j] = rows[i]; cc[j] = cols[i]; vv[j] = read_f(vals, fm, i);
            pp[j] = rr[j] >> 13;                   // partition 0..7
            rk[j] = atomicAdd(&hist[pp[j]], 1);    // LDS rank
          } else {
            pp[j] = -1;
          }
        }
        __syncthreads();
        if (tid == 0) {
          int s = 0;
#pragma unroll
          for (int q = 0; q < 8; ++q) { pfx[q] = s; s += hist[q]; }
        }
        if (tid < 8)
          gbase[tid] = atomicAdd(&binfill[(xcd << 4) + tid], hist[tid]);
        __syncthreads();
        // stage partition-sorted
#pragma unroll
        for (int j = 0; j < 4; ++j) {
          if (pp[j] >= 0)
            stage[pfx[pp[j]] + rk[j]] =
                make_int2((rr[j] << 16) | cc[j], __float_as_int(vv[j]));
        }
        __syncthreads();
        // coalesced flush
        int total = pfx[7] + hist[7];
        for (int k = tid; k < total; k += 256) {
          int p = 0;
#pragma unroll
          for (int q = 1; q < 8; ++q) p += (k >= pfx[q]);
          int2 ent = stage[k];
          int pos = gbase[p] + (k - pfx[p]);
          if (pos < cap) {
            bins[(size_t)((xcd << 3) + p) * cap + pos] = ent;
          } else {  // overflow (skewed rows): pre-assign rank, append to ovf
            int r = ((unsigned int)ent.x) >> 16;
            int orank = atomicAdd(&cnt_ovf[r], 1);
            int op = atomicAdd(&binfill[128], 1);
            ovf[op] = make_int4(r, ent.x & 0xFFFF, ent.y, orank);
          }
        }
        __syncthreads();            // protect pfx/hist before next tile
      }
    } else {
      // fallback (N > 65535): sharded atomic hist; pass 2 direct-scatters
      int* cnt_s = h8 + (size_t)xcd * Nrows;
      int i = blockIdx.x * blockDim.x + threadIdx.x;
      int stride = BIN_BLOCKS * blockDim.x;
      for (; i < E; i += stride) atomicAdd(&cnt_s[rows[i]], 1);
    }
  } else {
    // x -> bf16 frag conversion (only when x is f32)
    if (fm == 1) return;
    int nx4 = nx / 4;
    int i = (blockIdx.x - BIN_BLOCKS) * blockDim.x + threadIdx.x;
    int stride = (gridDim.x - BIN_BLOCKS) * blockDim.x;
    for (; i < nx4; i += stride) {
      int m = i / (K1 / 4);
      int k0 = (i - m * (K1 / 4)) * 4;
      f32x4 v = ((const f32x4*)x)[i];
      ushort_t p0 = f2bf(v[0]), p1 = f2bf(v[1]), p2 = f2bf(v[2]), p3 = f2bf(v[3]);
      size_t o = frag_off(m, k0, K1);
      *(u32x2*)(xbf + o) = (u32x2){
          (unsigned int)p0 | ((unsigned int)p1 << 16),
          (unsigned int)p2 | ((unsigned int)p3 << 16)};
    }
  }
}

// ---------------- pass 1.5: per-(xcd,partition) LDS histogram -> h8 ---------
__global__ __launch_bounds__(256) void count_kernel(
    const int2* __restrict__ bins, const int* __restrict__ binfill,
    int cap, int* __restrict__ h8, int Nrows, int use_bins) {
  if (!use_bins) return;
  int x = blockIdx.x >> 3, p = blockIdx.x & 7;
  __shared__ int hist[8192];
  for (int i = threadIdx.x; i < 8192; i += 256) hist[i] = 0;
  __syncthreads();
  int n = binfill[x * 16 + p];
  if (n > cap) n = cap;
  const int2* bp = bins + (size_t)((x << 3) + p) * cap;
  for (int e = threadIdx.x; e < n; e += 256) {
    int r = ((unsigned int)bp[e].x) >> 16;
    atomicAdd(&hist[r & 8191], 1);
  }
  __syncthreads();
  int r0 = p << 13;
  for (int i = threadIdx.x; i < 8192; i += 256) {
    int r = r0 + i;
    if (r < Nrows) h8[(size_t)x * Nrows + r] = hist[i];
  }
}

// ---------------- single-pass scan: shard-sum + lookback + cursor bases -----
__global__ __launch_bounds__(256) void scan_fused_kernel(
    const int* __restrict__ h8, const int* __restrict__ cnt_ovf,
    int* __restrict__ pub, int* __restrict__ row_start,
    int* __restrict__ sb8, int n) {
  int b = blockIdx.x, t = threadIdx.x;
  int i = b * 256 + t;
  int hx[8];
  int v = 0, ov = 0;
  if (i < n) {
#pragma unroll
    for (int x = 0; x < 8; ++x) { hx[x] = h8[(size_t)x * n + i]; v += hx[x]; }
    ov = cnt_ovf[i];
  } else {
#pragma unroll
    for (int x = 0; x < 8; ++x) hx[x] = 0;
  }
  int vt = v + ov;
  __shared__ int s[256];
  s[t] = vt;
  __syncthreads();
  for (int off = 1; off < 256; off <<= 1) {
    int a_ = s[t];
    int y_ = (t >= off) ? s[t - off] : 0;
    __syncthreads();
    s[t] = a_ + y_;
    __syncthreads();
  }
  int incl = s[t];
  int total = s[255];
  if (t == 0)
    __hip_atomic_store(&pub[b], (total << 1) | 1, __ATOMIC_RELEASE,
                       __HIP_MEMORY_SCOPE_AGENT);
  int contrib = 0;
  for (int t0 = t; t0 < b; t0 += 256) {
    int p;
    do {
      p = __hip_atomic_load(&pub[t0], __ATOMIC_ACQUIRE,
                            __HIP_MEMORY_SCOPE_AGENT);
    } while (!(p & 1));
    contrib += (p >> 1);
  }
  __syncthreads();                 // s[] reuse barrier
  s[t] = contrib;
  __syncthreads();
  for (int off = 128; off > 0; off >>= 1) {
    if (t < off) s[t] += s[t + off];
    __syncthreads();
  }
  int base = s[0];
  int rs = base + incl - vt;       // exclusive
  if (i < n) {
    row_start[i] = rs;
    int acc = rs;
#pragma unroll
    for (int x = 0; x < 8; ++x) { sb8[(size_t)x * n + i] = acc; acc += hx[x]; }
    sb8[(size_t)8 * n + i] = acc;  // ovf base
  }
  if (i == n - 1) row_start[n] = base + incl;
}

// ---------------- GEMM body (r15 core, PANEL-MAJOR store) -------------------
template<int KC>
__device__ __forceinline__ void load_afrag(const ushort_t* __restrict__ A,
                                           const ushort_t* __restrict__ Xrow,
                                           bool rowA, int mtile, int K,
                                           int lane, int mr, int quad, int M,
                                           bf16x8* dst) {
  if (rowA) {
    int rr = mtile * 16 + mr;
    if (rr >= M) rr = M - 1;
    const ushort_t* ap = Xrow + (size_t)rr * K + quad * 8;
#pragma unroll
    for (int kc = 0; kc < KC; ++kc) dst[kc] = *(const bf16x8*)(ap + kc * 32);
  } else {
    const ushort_t* ap = A + (size_t)mtile * 16 * K + lane * 8;
#pragma unroll
    for (int kc = 0; kc < KC; ++kc) dst[kc] = *(const bf16x8*)(ap + kc * 512);
  }
}

template<int KC>
__device__ __forceinline__ void gemm_dev(
    int vbid, int nblk, int tid,
    const ushort_t* __restrict__ A, const ushort_t* __restrict__ Xrow, int fm,
    const ushort_t* __restrict__ Whi, const ushort_t* __restrict__ Wlo,
    const float* __restrict__ bias, ushort_t* __restrict__ g, int Np,
    int M, int nct) {
  const int K = KC * 32;
  int wave = tid >> 6, lane = tid & 63;
  int gw = vbid * 4 + wave;
  int NW = nblk * 4;
  int mr = lane & 15, quad = lane >> 4;
  int ct = gw % nct;
  int nrt = (M + 15) >> 4;
  int ntasks = nct * nrt;
  if (gw >= ntasks) return;

  bool rowA = (Xrow != nullptr) && (fm != 0);

  bf16x8 wh[KC], wl[KC];
  {
    const ushort_t* wp = Whi + (size_t)ct * 16 * K + lane * 8;
    const ushort_t* wq = Wlo + (size_t)ct * 16 * K + lane * 8;
#pragma unroll
    for (int kc = 0; kc < KC; ++kc) {
      wh[kc] = *(const bf16x8*)(wp + kc * 512);
      wl[kc] = *(const bf16x8*)(wq + kc * 512);
    }
  }
  int col = ct * 16 + mr;
  float bv = bias[col];
  // panel-major G destination: panel = col>>5, within-panel col&31
  ushort_t* gp = g + (size_t)(col >> 5) * Np * 32 + (col & 31);

  int task = gw;
  bf16x8 af[KC];
  load_afrag<KC>(A, Xrow, rowA, task / nct, K, lane, mr, quad, M, af);

#pragma unroll 1
  for (;;) {
    int next = task + NW;
    bool has_next = next < ntasks;
    bf16x8 afn[KC];
    if (has_next)
      load_afrag<KC>(A, Xrow, rowA, next / nct, K, lane, mr, quad, M, afn);

    f32x4 acc[4];
#pragma unroll
    for (int t = 0; t < 4; ++t) acc[t] = (f32x4){0.f, 0.f, 0.f, 0.f};
#pragma unroll
    for (int kc = 0; kc < KC; ++kc) {
      acc[(2 * kc) & 3] = __builtin_amdgcn_mfma_f32_16x16x32_bf16(af[kc], wh[kc], acc[(2 * kc) & 3], 0, 0, 0);
      acc[(2 * kc + 1) & 3] = __builtin_amdgcn_mfma_f32_16x16x32_bf16(af[kc], wl[kc], acc[(2 * kc + 1) & 3], 0, 0, 0);
    }
    int m0 = (task / nct) * 16;
#pragma unroll
    for (int r = 0; r < 4; ++r) {
      int row = m0 + quad * 4 + r;
      float s = ((acc[0][r] + acc[1][r]) + (acc[2][r] + acc[3][r])) + bv;
      if (row < M) gp[(size_t)row * 32] = f2bf(s);
    }
    if (!has_next) break;
#pragma unroll
    for (int kc = 0; kc < KC; ++kc) af[kc] = afn[kc];
    task = next;
  }
}

template<int KC>
__global__ __launch_bounds__(256) void gemm_breg_kernel(
    const ushort_t* __restrict__ A,
    const ushort_t* __restrict__ Xrow, const int* __restrict__ fm_p,
    const ushort_t* __restrict__ Whi, const ushort_t* __restrict__ Wlo,
    const float* __restrict__ bias, ushort_t* __restrict__ g, int Np,
    int M, int nct) {
  gemm_dev<KC>(blockIdx.x, gridDim.x, threadIdx.x, A, Xrow, *fm_p,
               Whi, Wlo, bias, g, Np, M, nct);
}

// ---------------- pass 2 (atomic-free scatter, blocks 0..63) + GEMM-1 -------
__global__ __launch_bounds__(256) void scatter_gemm_kernel(
    const int2* __restrict__ bins, const int* __restrict__ binfill,
    const int* __restrict__ row_start, int* __restrict__ fill,
    const int* __restrict__ sb8, int Nrows,
    int2* __restrict__ ecv, int cap, const int4* __restrict__ ovf,
    const int* __restrict__ rows, const int* __restrict__ cols,
    const void* __restrict__ vals, const int* __restrict__ fm_p,
    int use_bins, int E,
    const ushort_t* __restrict__ A, const ushort_t* __restrict__ Xrow,
    const ushort_t* __restrict__ Whi, const ushort_t* __restrict__ Wlo,
    const float* __restrict__ bias, ushort_t* __restrict__ g, int Np,
    int M, int nct) {
  __shared__ int sbl[8192];
  if (blockIdx.x >= 64) {
    gemm_dev<8>(blockIdx.x - 64, 1024, threadIdx.x, A, Xrow, *fm_p,
                Whi, Wlo, bias, g, Np, M, nct);
    return;
  }
  if (use_bins) {
    int x = blockIdx.x >> 3, p = blockIdx.x & 7;
    int r0 = p << 13;
    for (int i = threadIdx.x; i < 8192; i += 256) {
      int r = r0 + i;
      sbl[i] = (r < Nrows) ? sb8[(size_t)x * Nrows + r] : 0;
    }
    __syncthreads();
    int n = binfill[x * 16 + p];
    if (n > cap) n = cap;
    const int2* bp = bins + (size_t)((x << 3) + p) * cap;
    for (int e = threadIdx.x; e < n; e += 256) {
      int2 ent = bp[e];
      int r = ((unsigned int)ent.x) >> 16;
      int pos = atomicAdd(&sbl[r & 8191], 1);     // LDS cursor, no global RMW
      ecv[pos] = make_int2(ent.x & 0xFFFF, ent.y);
    }
    // ovf drain (rank pre-assigned in pass 1; no atomics)
    int ovfn = binfill[128];
    for (int e = blockIdx.x * 256 + (int)threadIdx.x; e < ovfn; e += 64 * 256) {
      int4 t = ovf[e];
      ecv[sb8[(size_t)8 * Nrows + t.x] + t.w] = make_int2(t.y, t.z);
    }
  } else {
    int fm = *fm_p;
    for (int i = blockIdx.x * 256 + (int)threadIdx.x; i < E; i += 64 * 256) {
      int r = rows[i];
      int pos = atomicAdd(&fill[r], 1);
      ecv[row_start[r] + pos] = make_int2(cols[i], __float_as_int(read_f(vals, fm, i)));
    }
  }
}

// ---------------- SpMM v10: panel-major gathers -----------------------------
// Block = 8 rows x 32-feature panel (panel = blockIdx % npanel -> one XCD's
// L2 holds the 3.2MB panel). Half-wave per row: lanes f=0..31, 8-deep edge
// chunks (broadcast ecv reads, 64B/edge panel gathers -> L2-hit).
// MODE 1: leaky+mask -> bf16 frag (LDS stage, 128B-contiguous quad flush).
// MODE 0: f32 row-major out (128B/row-half contiguous).
template<int MODE>
__global__ __launch_bounds__(256) void spmmp_kernel(
    const int* __restrict__ row_start, const int2* __restrict__ ecv,
    const ushort_t* __restrict__ Gp, int D, int Np,
    const void* __restrict__ mask, const int* __restrict__ mmode_p,
    void* __restrict__ outp, int N, int npanel) {
  __shared__ ushort_t stage[256];          // 8 rows x 32 feats (MODE 1)
  int p = blockIdx.x % npanel;
  int rg = blockIdx.x / npanel;
  int wave = threadIdx.x >> 6, lane = threadIdx.x & 63;
  int half = lane >> 5, f = lane & 31;
  int r = rg * 8 + wave * 2 + half;
  bool active = r < N;
  const ushort_t* G0 = Gp + (size_t)p * Np * 32;
  float a = 0.f;

  // hoisted mask load
  bool keep = true;
  if (MODE == 1 && active) {
    size_t om = (size_t)r * D + p * 32 + f;
    int mm = *mmode_p;
    if (mm == 1 || mm == 2) keep = ((const unsigned int*)mask)[om] != 0u;
    else if (mm == 3)       keep = ((const ushort_t*)mask)[om] != 0;
    else                    keep = ((const unsigned char*)mask)[om] != 0;
  }

  if (active) {
    int e = row_start[r], e1 = row_start[r + 1];
    for (; e + 8 <= e1; e += 8) {
      int2 cv[8];
#pragma unroll
      for (int j = 0; j < 8; ++j) cv[j] = ecv[e + j];
      ushort_t g[8];
#pragma unroll
      for (int j = 0; j < 8; ++j) g[j] = G0[(size_t)cv[j].x * 32 + f];
#pragma unroll
      for (int j = 0; j < 8; ++j) a += __int_as_float(cv[j].y) * bf2f(g[j]);
    }
    if (e < e1) {
      int idx[8]; float v[8];
#pragma unroll
      for (int j = 0; j < 8; ++j) {
        int ee = e + j;
        bool ok = ee < e1;
        int2 cv = ecv[ok ? ee : e1 - 1];
        idx[j] = cv.x;
        v[j] = ok ? __int_as_float(cv.y) : 0.f;
      }
      ushort_t g[8];
#pragma unroll
      for (int j = 0; j < 8; ++j) g[j] = G0[(size_t)idx[j] * 32 + f];
#pragma unroll
      for (int j = 0; j < 8; ++j) a += v[j] * bf2f(g[j]);
    }
  }

  if (MODE == 1) {
    float t = (a >= 0.f) ? a : 0.2f * a;           // leaky relu 0.2
    t = keep ? t * 1.25f : 0.f;                    // keep = 1/(1-0.2)
    stage[threadIdx.x] = active ? f2bf(t) : (ushort_t)0;  // [row8][f] == tid
    __syncthreads();
    // flush: frag chunk for (16-row tile, kc=p): our 8 rows occupy, per quad,
    // a contiguous 64-elem (128B) segment. 64 threads x 8B pieces.
    if (threadIdx.x < 64) {
      int k = threadIdx.x;
      int quad = k >> 4, idx = k & 15;
      int row = idx >> 1, s = (idx & 1) * 4;
      int r0 = rg * 8;
      size_t base = (size_t)(r0 >> 4) * 16 * D + ((size_t)p << 9) +
                    (size_t)(r0 & 15) * 8;
      size_t goff = base + quad * 128 + idx * 4;
      *(u32x2*)((ushort_t*)outp + goff) =
          *(const u32x2*)(stage + row * 32 + quad * 8 + s);
    }
  } else {
    if (active) ((float*)outp)[(size_t)r * D + p * 32 + f] = a;
  }
}

// ---------------- launch ----------------
extern "C" void kernel_launch(void* const* d_in, const int* in_sizes, int n_in,
                              void* d_out, int out_size, void* d_ws, size_t ws_size,
                              hipStream_t stream) {
  const void* x     = d_in[0];
  const int*  rows  = (const int*)d_in[1];
  const int*  cols  = (const int*)d_in[2];
  const void* vals  = d_in[3];
  const void* W1    = d_in[4];
  const void* b1    = d_in[5];
  const void* W2    = d_in[6];
  const void* b2    = d_in[7];
  const void* W3    = d_in[8];
  const void* b3    = d_in[9];
  const void* mask1 = d_in[10];
  const void* mask2 = d_in[11];

  const int H1  = in_sizes[5];            // 256
  const int H2  = in_sizes[7];            // 128
  const int OUT = in_sizes[9];            // 64
  const int IN  = in_sizes[4] / H1;       // 256
  const int N   = in_sizes[0] / IN;       // 50000
  const int E   = in_sizes[1];            // 800000
  const int W1n = in_sizes[4], W2n = in_sizes[6], W3n = in_sizes[8];
  const int Np  = ((N + 15) / 16) * 16;
  const int CAP = (E >> 5) + 2048;        // per-bin cap
  const int use_bins = (N <= 65535) ? 1 : 0;
  const int P = (N + 255) / 256;          // scan blocks (<=256 for lookback)

  char* ws = (char*)d_ws;
  size_t off = 0;
  auto alloc = [&](size_t bytes) -> void* {
    void* p = ws + off;
    off = (off + bytes + 255) & ~(size_t)255;
    return p;
  };
  int*      modes     = (int*)alloc(4 * 4);
  int*      row_start = (int*)alloc((size_t)(N + 1) * 4);
  // meta (zeroed): [h8: 8N | cnt_ovf: N | fill: N | binfill: 256 | pub: 256]
  int*      meta      = (int*)alloc(((size_t)10 * N + 512) * 4);
  int*      sb8       = (int*)alloc((size_t)9 * N * 4);        // cursor bases
  int2*     ecv       = (int2*)alloc((size_t)E * 8);
  int2*     bins      = (int2*)alloc((size_t)64 * CAP * 8);
  int4*     ovf       = (int4*)alloc((size_t)E * 16);
  ushort_t* whi       = (ushort_t*)alloc((size_t)(W1n + W2n + W3n) * 2);
  ushort_t* wlo       = (ushort_t*)alloc((size_t)(W1n + W2n + W3n) * 2);
  float*    biasf     = (float*)alloc((size_t)(H1 + H2 + OUT) * 4);
  ushort_t* bufA      = (ushort_t*)alloc((size_t)Np * H1 * 2);   // frag / G3
  ushort_t* bufB      = (ushort_t*)alloc((size_t)Np * H1 * 2);   // panel G
  // bufC ALIASED onto [bins|ovf] (bins dead after pass 2; bufC first written
  // by spmm1 which launches after scatter_gemm completes)
  ushort_t* bufC      = (ushort_t*)bins;
  // total ~89 MB (<=110 MB proven safe in r3)

  int* fmode   = modes;
  int* mm1     = modes + 1;
  int* mm2     = modes + 2;
  int* h8      = meta;                     // 8N (main: plain; fallback: atomic)
  int* cnt_ovf = meta + 8 * N;             // N
  int* fill    = meta + 9 * N;             // N (fallback only)
  int* binfill = meta + 10 * N;            // 128 bin ctrs + ovf ctr [128]
  int* pub     = meta + 10 * N + 256;      // 256 lookback slots
  ushort_t* w1hi = whi,             *w1lo = wlo;
  ushort_t* w2hi = whi + W1n,       *w2lo = wlo + W1n;
  ushort_t* w3hi = whi + W1n + W2n, *w3lo = wlo + W1n + W2n;

  // 1. prep: sniff + W/bias convert (self-sniff) + zero meta region
  prep_kernel<<<512, 256, 0, stream>>>(
      x, mask1, mask2, modes, meta, 10 * N + 512,
      W1, W2, W3, b1, b2, b3, whi, wlo, biasf,
      W1n, W2n, W3n, H1, H2, OUT, IN, H1, H2);

  // 2. binning (1024 blocks, no per-edge global atomics) + x-frag convert
  hist_bin_kernel<<<2048, 256, 0, stream>>>(
      rows, cols, vals, fmode, h8, cnt_ovf, binfill, bins, CAP, use_bins, ovf,
      E, N, x, bufA, IN, N * IN);

  // 3. per-(xcd,partition) LDS histogram -> h8 (no global atomics)
  count_kernel<<<64, 256, 0, stream>>>(bins, binfill, CAP, h8, N, use_bins);

  // 4. single-pass CSR scan (lookback) + shard cursor bases sb8
  scan_fused_kernel<<<P, 256, 0, stream>>>(h8, cnt_ovf, pub, row_start, sb8, N);

  // 5. pass 2 (atomic-free scatter, 64 blocks) || GEMM-1 (1024 blocks)
  //    GEMM-1 writes G1 panel-major into bufB.
  scatter_gemm_kernel<<<1088, 256, 0, stream>>>(
      bins, binfill, row_start, fill, sb8, N, ecv, CAP, ovf,
      rows, cols, vals, fmode, use_bins, E,
      bufA, (const ushort_t*)x, w1hi, w1lo, biasf, bufB, Np, N, H1 / 16);

  const int RGB = (N + 7) / 8;             // row-groups of 8
  const int GEMM_BLOCKS = 1024;

  // 6-10. panel-SpMM / GEMM chain
  // spmm1: G1(bufB, 8 panels) -> leaky+mask1 -> frag bufC (K=H1)
  spmmp_kernel<1><<<8 * RGB, 256, 0, stream>>>(
      row_start, ecv, bufB, H1, Np, mask1, mm1, bufC, N, 8);
  // gemm2: bufC frag -> G2 panel-major (bufB, 4 panels)
  gemm_breg_kernel<8><<<GEMM_BLOCKS, 256, 0, stream>>>(
      bufC, nullptr, fmode, w2hi, w2lo, biasf + H1, bufB, Np, N, H2 / 16);
  // spmm2: G2 -> leaky+mask2 -> frag bufA (K=H2)
  spmmp_kernel<1><<<4 * RGB, 256, 0, stream>>>(
      row_start, ecv, bufB, H2, Np, mask2, mm2, bufA, N, 4);
  // gemm3: bufA frag -> G3 panel-major (bufB, 2 panels)
  gemm_breg_kernel<4><<<GEMM_BLOCKS, 256, 0, stream>>>(
      bufA, nullptr, fmode, w3hi, w3lo, biasf + H1 + H2, bufB, Np, N, OUT / 16);
  // spmm3: G3 -> f32 row-major d_out
  spmmp_kernel<0><<<2 * RGB, 256, 0, stream>>>(
      row_start, ecv, bufB, OUT, Np, nullptr, fmode, d_out, N, 2);
}